// Round 4
// baseline (2420.876 us; speedup 1.0000x reference)
//
#include <hip/hip_runtime.h>

#define THREADS 256
#define NB_SHIFT 7              // 128 nodes per bucket
#define NB 128

// ---------------------------------------------------------------------------
// Edge-index dtype detection: little-endian int64 values < 2^31 have all-zero
// odd 32-bit words. flag=1 -> int64 layout, flag=0 -> int32 layout.
// ---------------------------------------------------------------------------
__global__ __launch_bounds__(64)
void detect_kernel(const unsigned* __restrict__ ei_words, int* __restrict__ flag) {
    if (threadIdx.x == 0 && blockIdx.x == 0) {
        int allzero = 1;
        for (int i = 0; i < 64; ++i) {
            if (ei_words[2 * i + 1] != 0u) { allzero = 0; break; }
        }
        *flag = allzero;
    }
}

__device__ __forceinline__ void load_edge(const void* ei, int is64, int E, int i,
                                          int& s, int& t) {
    if (is64) {
        const long long* p = (const long long*)ei;
        s = (int)p[i];
        t = (int)p[E + i];
    } else {
        const int* p = (const int*)ei;
        s = p[i];
        t = p[E + i];
    }
}

// ---------------------------------------------------------------------------
// Coarse histogram: counts per (bucket = dst>>7, group = blockIdx&7).
// Counter array is ~25 KB -> atomics stay in L2.
// ---------------------------------------------------------------------------
__global__ __launch_bounds__(THREADS)
void ccount_kernel(const void* __restrict__ ei, const int* __restrict__ flag,
                   int* __restrict__ cc, int E) {
    int i = blockIdx.x * THREADS + threadIdx.x;
    if (i >= E) return;
    int s, t;
    load_edge(ei, *flag, E, i, s, t);
    (void)s;
    const int g = blockIdx.x & 7;
    atomicAdd(&cc[((t >> NB_SHIFT) << 3) + g], 1);
}

// ---------------------------------------------------------------------------
// Three-kernel exclusive scan (generic n; used on the 6256 coarse counters).
// ---------------------------------------------------------------------------
__global__ __launch_bounds__(256)
void scan_partial_kernel(const int* __restrict__ cnt, int* __restrict__ bsum, int n) {
    const int base = blockIdx.x * 1024;
    int v = 0;
    for (int i = threadIdx.x; i < 1024; i += 256) {
        const int idx = base + i;
        v += (idx < n) ? cnt[idx] : 0;
    }
#pragma unroll
    for (int off = 32; off > 0; off >>= 1) v += __shfl_down(v, off, 64);
    __shared__ int ws[4];
    if ((threadIdx.x & 63) == 0) ws[threadIdx.x >> 6] = v;
    __syncthreads();
    if (threadIdx.x == 0) bsum[blockIdx.x] = ws[0] + ws[1] + ws[2] + ws[3];
}

__global__ __launch_bounds__(64)
void scan_bsum_kernel(int* __restrict__ bsum, int* __restrict__ total, int nb) {
    if (threadIdx.x == 0) {
        int run = 0;
        for (int i = 0; i < nb; ++i) { int t = bsum[i]; bsum[i] = run; run += t; }
        *total = run;
    }
}

__global__ __launch_bounds__(256)
void scan_final_kernel(const int* __restrict__ cnt, const int* __restrict__ bsum,
                       int* __restrict__ rowptr, int* __restrict__ wptr, int n) {
    const int base = blockIdx.x * 1024 + threadIdx.x * 4;
    int a0 = 0, a1 = 0, a2 = 0, a3 = 0;
    if (base + 0 < n) a0 = cnt[base + 0];
    if (base + 1 < n) a1 = cnt[base + 1];
    if (base + 2 < n) a2 = cnt[base + 2];
    if (base + 3 < n) a3 = cnt[base + 3];
    const int mysum = a0 + a1 + a2 + a3;
    const int lane = threadIdx.x & 63;
    const int wid  = threadIdx.x >> 6;
    int incl = mysum;
#pragma unroll
    for (int off = 1; off < 64; off <<= 1) {
        int t = __shfl_up(incl, off, 64);
        if (lane >= off) incl += t;
    }
    __shared__ int ws[4];
    if (lane == 63) ws[wid] = incl;
    __syncthreads();
    int woff = 0;
    for (int w = 0; w < wid; ++w) woff += ws[w];
    int pre = bsum[blockIdx.x] + woff + (incl - mysum);
    if (base + 0 < n) { rowptr[base + 0] = pre; wptr[base + 0] = pre; } pre += a0;
    if (base + 1 < n) { rowptr[base + 1] = pre; wptr[base + 1] = pre; } pre += a1;
    if (base + 2 < n) { rowptr[base + 2] = pre; wptr[base + 2] = pre; } pre += a2;
    if (base + 3 < n) { rowptr[base + 3] = pre; wptr[base + 3] = pre; }
}

// ---------------------------------------------------------------------------
// Coarse placement: append packed edge (src | dstlocal<<17) to its
// (bucket, group) sub-region. Same blockIdx->g mapping as ccount.
// ---------------------------------------------------------------------------
__global__ __launch_bounds__(THREADS)
void cplace_kernel(const void* __restrict__ ei, const int* __restrict__ flag,
                   int* __restrict__ cptr, unsigned* __restrict__ ebuf, int E) {
    int i = blockIdx.x * THREADS + threadIdx.x;
    if (i >= E) return;
    int s, t;
    load_edge(ei, *flag, E, i, s, t);
    const int g = blockIdx.x & 7;
    const int pos = atomicAdd(&cptr[((t >> NB_SHIFT) << 3) + g], 1);
    ebuf[pos] = (unsigned)s | ((unsigned)(t & (NB - 1)) << 17);
}

// ---------------------------------------------------------------------------
// Bucket aggregation: block = bucket of 128 nodes. Edges (contiguous in ebuf)
// are accumulated into a padded LDS tile via ds_add_f32; degree counted in
// LDS. Epilogue: mean (+ q + bias, tanh if FUSE) -> dense row writes.
// D = 64. Row pad 65 floats spreads LDS banks across tl.
// ---------------------------------------------------------------------------
template <bool FUSE>
__global__ __launch_bounds__(THREADS)
void bucket_agg_kernel(const int* __restrict__ cbase, const unsigned* __restrict__ ebuf,
                       const float* __restrict__ p, const float* __restrict__ q,
                       const float* __restrict__ bias,
                       float* __restrict__ hout, int n, int E) {
    __shared__ float acc[NB][65];
    __shared__ int scnt[NB];
    const int b = blockIdx.x;
    for (int i = threadIdx.x; i < NB * 65; i += THREADS) ((float*)acc)[i] = 0.f;
    for (int i = threadIdx.x; i < NB; i += THREADS) scnt[i] = 0;
    __syncthreads();

    const int e0 = cbase[b << 3];
    const int e1 = cbase[(b + 1) << 3];
    const int c  = threadIdx.x & 15;   // float4 chunk lane
    const int eg = threadIdx.x >> 4;   // edge group 0..15

    for (int e = e0 + eg; e < e1; e += 16) {
        const unsigned w = ebuf[e];
        const int s  = (int)(w & 0x1FFFFu);
        const int tl = (int)(w >> 17);
        const float4 v = *(const float4*)(p + (size_t)s * 64 + 4 * c);
        float* row = &acc[tl][4 * c];
        atomicAdd(row + 0, v.x);
        atomicAdd(row + 1, v.y);
        atomicAdd(row + 2, v.z);
        atomicAdd(row + 3, v.w);
        if (c == 0) atomicAdd(&scnt[tl], 1);
    }
    __syncthreads();

    const int base = b * NB;
    for (int i = threadIdx.x; i < NB * 16; i += THREADS) {
        const int tl  = i >> 4;
        const int cc4 = i & 15;
        const int node = base + tl;
        if (node >= n) continue;
        const float inv = 1.0f / fmaxf((float)scnt[tl], 1.0f);
        float4 o;
        o.x = acc[tl][4 * cc4 + 0] * inv;
        o.y = acc[tl][4 * cc4 + 1] * inv;
        o.z = acc[tl][4 * cc4 + 2] * inv;
        o.w = acc[tl][4 * cc4 + 3] * inv;
        if (FUSE) {
            const float4 qv = *(const float4*)(q + (size_t)node * 64 + 4 * cc4);
            const float4 bv = *(const float4*)(bias + 4 * cc4);
            o.x = tanhf(o.x + qv.x + bv.x);
            o.y = tanhf(o.y + qv.y + bv.y);
            o.z = tanhf(o.z + qv.z + bv.z);
            o.w = tanhf(o.w + qv.w + bv.w);
        }
        *(float4*)(hout + (size_t)node * 64 + 4 * cc4) = o;
    }
}

// ---------------------------------------------------------------------------
// Dual GEMM: p = x @ Wl, q = x @ Wr.  [n, D_IN] x [D_IN, D_OUT] twice.
// ---------------------------------------------------------------------------
template <int D_IN, int D_OUT, int R>
__global__ __launch_bounds__(512)
void dual_gemm_kernel(const float* __restrict__ x,
                      const float* __restrict__ Wl, const float* __restrict__ Wr,
                      float* __restrict__ p, float* __restrict__ q, int n) {
    constexpr int TPR = D_OUT / 4;
    constexpr int RPB = (512 / TPR) * R;
    __shared__ float sWl[D_IN * D_OUT];
    __shared__ float sWr[D_IN * D_OUT];
    for (int i = threadIdx.x; i < D_IN * D_OUT / 4; i += 512) {
        ((float4*)sWl)[i] = ((const float4*)Wl)[i];
        ((float4*)sWr)[i] = ((const float4*)Wr)[i];
    }
    __syncthreads();
    const int cg   = threadIdx.x % TPR;
    const int rs   = threadIdx.x / TPR;
    const int row0 = blockIdx.x * RPB + rs * R;
    float4 aL[R], aR[R];
#pragma unroll
    for (int r = 0; r < R; ++r) {
        aL[r] = make_float4(0.f, 0.f, 0.f, 0.f);
        aR[r] = make_float4(0.f, 0.f, 0.f, 0.f);
    }
#pragma unroll 4
    for (int k4 = 0; k4 < D_IN / 4; ++k4) {
        float4 xv[R];
#pragma unroll
        for (int r = 0; r < R; ++r) {
            const int row = min(row0 + r, n - 1);
            xv[r] = *(const float4*)(x + (size_t)row * D_IN + 4 * k4);
        }
#pragma unroll
        for (int j = 0; j < 4; ++j) {
            const float4 wl = *(const float4*)(sWl + (4 * k4 + j) * D_OUT + 4 * cg);
            const float4 wr = *(const float4*)(sWr + (4 * k4 + j) * D_OUT + 4 * cg);
#pragma unroll
            for (int r = 0; r < R; ++r) {
                const float a = ((const float*)&xv[r])[j];
                aL[r].x += a * wl.x; aL[r].y += a * wl.y;
                aL[r].z += a * wl.z; aL[r].w += a * wl.w;
                aR[r].x += a * wr.x; aR[r].y += a * wr.y;
                aR[r].z += a * wr.z; aR[r].w += a * wr.w;
            }
        }
    }
#pragma unroll
    for (int r = 0; r < R; ++r) {
        const int row = row0 + r;
        if (row < n) {
            *(float4*)(p + (size_t)row * D_OUT + 4 * cg) = aL[r];
            *(float4*)(q + (size_t)row * D_OUT + 4 * cg) = aR[r];
        }
    }
}

// ---------------------------------------------------------------------------
// Fused layer (layer 2): hout = tanh(agg @ Wl + hin @ Wr + b), 64 -> 128.
// ---------------------------------------------------------------------------
template <int D_IN, int D_OUT, int R>
__global__ __launch_bounds__(512)
void layer_kernel(const float* __restrict__ agg, const float* __restrict__ hin,
                  const float* __restrict__ Wl, const float* __restrict__ Wr,
                  const float* __restrict__ bias,
                  float* __restrict__ hout, int n) {
    constexpr int TPR = D_OUT / 4;
    constexpr int RPB = (512 / TPR) * R;
    __shared__ float sWl[D_IN * D_OUT];
    __shared__ float sWr[D_IN * D_OUT];
    __shared__ float sb[D_OUT];
    for (int i = threadIdx.x; i < D_IN * D_OUT / 4; i += 512) {
        ((float4*)sWl)[i] = ((const float4*)Wl)[i];
        ((float4*)sWr)[i] = ((const float4*)Wr)[i];
    }
    if (threadIdx.x < D_OUT) sb[threadIdx.x] = bias[threadIdx.x];
    __syncthreads();
    const int cg   = threadIdx.x % TPR;
    const int rs   = threadIdx.x / TPR;
    const int row0 = blockIdx.x * RPB + rs * R;
    float4 acc[R];
#pragma unroll
    for (int r = 0; r < R; ++r) acc[r] = make_float4(0.f, 0.f, 0.f, 0.f);
#pragma unroll 4
    for (int k4 = 0; k4 < D_IN / 4; ++k4) {
        float4 av[R], hv[R];
#pragma unroll
        for (int r = 0; r < R; ++r) {
            const int row = min(row0 + r, n - 1);
            av[r] = *(const float4*)(agg + (size_t)row * D_IN + 4 * k4);
            hv[r] = *(const float4*)(hin + (size_t)row * D_IN + 4 * k4);
        }
#pragma unroll
        for (int j = 0; j < 4; ++j) {
            const float4 wl = *(const float4*)(sWl + (4 * k4 + j) * D_OUT + 4 * cg);
            const float4 wr = *(const float4*)(sWr + (4 * k4 + j) * D_OUT + 4 * cg);
#pragma unroll
            for (int r = 0; r < R; ++r) {
                const float a = ((const float*)&av[r])[j];
                const float b = ((const float*)&hv[r])[j];
                acc[r].x += a * wl.x + b * wr.x;
                acc[r].y += a * wl.y + b * wr.y;
                acc[r].z += a * wl.z + b * wr.z;
                acc[r].w += a * wl.w + b * wr.w;
            }
        }
    }
#pragma unroll
    for (int r = 0; r < R; ++r) {
        const int row = row0 + r;
        if (row < n) {
            float4 o;
            o.x = tanhf(acc[r].x + sb[4 * cg + 0]);
            o.y = tanhf(acc[r].y + sb[4 * cg + 1]);
            o.z = tanhf(acc[r].z + sb[4 * cg + 2]);
            o.w = tanhf(acc[r].w + sb[4 * cg + 3]);
            *(float4*)(hout + (size_t)row * D_OUT + 4 * cg) = o;
        }
    }
}

// ---------------------------------------------------------------------------
// Head: out = h @ Wlin + blin   ([n,64] x [64,10])
// ---------------------------------------------------------------------------
__global__ __launch_bounds__(THREADS)
void head_kernel(const float* __restrict__ h, const float* __restrict__ W,
                 const float* __restrict__ bias, float* __restrict__ out, int n) {
    __shared__ float sW[64 * 10];
    __shared__ float sb[10];
    for (int i = threadIdx.x; i < 640; i += THREADS) sW[i] = W[i];
    if (threadIdx.x < 10) sb[threadIdx.x] = bias[threadIdx.x];
    __syncthreads();
    int idx = blockIdx.x * THREADS + threadIdx.x;
    if (idx >= n * 10) return;
    int row = idx / 10;
    int col = idx - row * 10;
    const float* __restrict__ hr = h + (size_t)row * 64;
    float acc = sb[col];
#pragma unroll 16
    for (int k = 0; k < 64; ++k) acc += hr[k] * sW[k * 10 + col];
    out[idx] = acc;
}

extern "C" void kernel_launch(void* const* d_in, const int* in_sizes, int n_in,
                              void* d_out, int out_size, void* d_ws, size_t ws_size,
                              hipStream_t stream) {
    const float* x    = (const float*)d_in[0];
    const void*  ei   = d_in[1];
    const float* W1l  = (const float*)d_in[2];
    const float* W1r  = (const float*)d_in[3];
    const float* b1   = (const float*)d_in[4];
    const float* W2l  = (const float*)d_in[5];
    const float* W2r  = (const float*)d_in[6];
    const float* b2   = (const float*)d_in[7];
    const float* W3l  = (const float*)d_in[8];
    const float* W3r  = (const float*)d_in[9];
    const float* b3   = (const float*)d_in[10];
    const float* Wlin = (const float*)d_in[11];
    const float* blin = (const float*)d_in[12];
    float* out = (float*)d_out;

    const int n = in_sizes[0] / 128;   // 100000
    const int E = in_sizes[1] / 2;     // 1600000
    const int B = (n + NB - 1) / NB;   // buckets (782)
    const int C = B * 8;               // coarse counters

    // --- workspace carve-up (~140 MB) ---
    char* ws = (char*)d_ws;
    size_t off = 0;
    auto carve = [&](size_t bytes) {
        void* p = ws + off;
        off += (bytes + 255) & ~(size_t)255;
        return p;
    };
    int*      flag  = (int*)     carve(256);
    int*      cc    = (int*)     carve((size_t)C * 4);        // coarse counts
    int*      cbase = (int*)     carve((size_t)(C + 1) * 4);  // scan out (ro)
    int*      cptr  = (int*)     carve((size_t)C * 4);        // scan out (rw)
    int*      bsum  = (int*)     carve(4096);
    unsigned* ebuf  = (unsigned*)carve((size_t)E * 4);        // packed edges
    float*    p     = (float*)   carve((size_t)n * 64 * 4);   // proj / agg
    float*    q     = (float*)   carve((size_t)n * 64 * 4);
    float*    h1    = (float*)   carve((size_t)n * 64 * 4);
    float*    h2    = (float*)   carve((size_t)n * 128 * 4);
    float*    h3    = h1;   // h1 dead after layer 2
    (void)ws_size;

    const int eblocks = (E + THREADS - 1) / THREADS;
    const int cscan   = (C + 1023) / 1024;

    // --- coarse bucket sort (once; graph shared by all layers) ---
    detect_kernel<<<1, 64, 0, stream>>>((const unsigned*)ei, flag);
    hipMemsetAsync(cc, 0, (size_t)C * 4, stream);
    ccount_kernel<<<eblocks, THREADS, 0, stream>>>(ei, flag, cc, E);
    scan_partial_kernel<<<cscan, 256, 0, stream>>>(cc, bsum, C);
    scan_bsum_kernel<<<1, 64, 0, stream>>>(bsum, cbase + C, cscan);
    scan_final_kernel<<<cscan, 256, 0, stream>>>(cc, bsum, cbase, cptr, C);
    cplace_kernel<<<eblocks, THREADS, 0, stream>>>(ei, flag, cptr, ebuf, E);

    // --- layer 1: project-then-aggregate (mean(x)@W = mean(x@W)) ---
    dual_gemm_kernel<128, 64, 2><<<(n + 63) / 64, 512, 0, stream>>>(
        x, W1l, W1r, p, q, n);
    bucket_agg_kernel<true><<<B, THREADS, 0, stream>>>(
        cbase, ebuf, p, q, b1, h1, n, E);

    // --- layer 2: aggregate-then-project (64 -> 128) ---
    bucket_agg_kernel<false><<<B, THREADS, 0, stream>>>(
        cbase, ebuf, h1, nullptr, nullptr, p /*agg*/, n, E);
    layer_kernel<64, 128, 2><<<(n + 31) / 32, 512, 0, stream>>>(
        p /*agg*/, h1, W2l, W2r, b2, h2, n);

    // --- layer 3: project-then-aggregate ---
    dual_gemm_kernel<128, 64, 2><<<(n + 63) / 64, 512, 0, stream>>>(
        h2, W3l, W3r, p, q, n);
    bucket_agg_kernel<true><<<B, THREADS, 0, stream>>>(
        cbase, ebuf, p, q, b3, h3, n, E);

    // --- head ---
    head_kernel<<<(n * 10 + THREADS - 1) / THREADS, THREADS, 0, stream>>>(
        h3, Wlin, blin, out, n);
}

// Round 5
// 525.499 us; speedup vs baseline: 4.6068x; 4.6068x over previous
//
#include <hip/hip_runtime.h>

#define THREADS 256
#define NB_SHIFT 7              // 128 nodes per bucket
#define NB 128

typedef unsigned short ushort_t;

__device__ __forceinline__ unsigned short f2bf(float f) {
    unsigned u = __float_as_uint(f);
    u += 0x7fff + ((u >> 16) & 1);   // round-to-nearest-even
    return (unsigned short)(u >> 16);
}
__device__ __forceinline__ float bf2f(unsigned short s) {
    return __uint_as_float((unsigned)s << 16);
}
__device__ __forceinline__ float4 bf4_to_f4(ushort4 u) {
    return make_float4(bf2f(u.x), bf2f(u.y), bf2f(u.z), bf2f(u.w));
}
__device__ __forceinline__ ushort4 f4_to_bf4(float4 v) {
    ushort4 o;
    o.x = f2bf(v.x); o.y = f2bf(v.y); o.z = f2bf(v.z); o.w = f2bf(v.w);
    return o;
}

// ---------------------------------------------------------------------------
// Edge-index dtype detection: little-endian int64 values < 2^31 have all-zero
// odd 32-bit words. flag=1 -> int64 layout, flag=0 -> int32 layout.
// ---------------------------------------------------------------------------
__global__ __launch_bounds__(64)
void detect_kernel(const unsigned* __restrict__ ei_words, int* __restrict__ flag) {
    if (threadIdx.x == 0 && blockIdx.x == 0) {
        int allzero = 1;
        for (int i = 0; i < 64; ++i) {
            if (ei_words[2 * i + 1] != 0u) { allzero = 0; break; }
        }
        *flag = allzero;
    }
}

__device__ __forceinline__ void load_edge(const void* ei, int is64, int E, int i,
                                          int& s, int& t) {
    if (is64) {
        const long long* p = (const long long*)ei;
        s = (int)p[i];
        t = (int)p[E + i];
    } else {
        const int* p = (const int*)ei;
        s = p[i];
        t = p[E + i];
    }
}

// ---------------------------------------------------------------------------
// Coarse histogram: counts per (bucket = dst>>7, group = blockIdx&7).
// Counter array ~25 KB -> atomics stay in L2.
// ---------------------------------------------------------------------------
__global__ __launch_bounds__(THREADS)
void ccount_kernel(const void* __restrict__ ei, const int* __restrict__ flag,
                   int* __restrict__ cc, int E) {
    int i = blockIdx.x * THREADS + threadIdx.x;
    if (i >= E) return;
    int s, t;
    load_edge(ei, *flag, E, i, s, t);
    (void)s;
    const int g = blockIdx.x & 7;
    atomicAdd(&cc[((t >> NB_SHIFT) << 3) + g], 1);
}

// ---------------------------------------------------------------------------
// Three-kernel exclusive scan over the C=B*8 coarse counters.
// ---------------------------------------------------------------------------
__global__ __launch_bounds__(256)
void scan_partial_kernel(const int* __restrict__ cnt, int* __restrict__ bsum, int n) {
    const int base = blockIdx.x * 1024;
    int v = 0;
    for (int i = threadIdx.x; i < 1024; i += 256) {
        const int idx = base + i;
        v += (idx < n) ? cnt[idx] : 0;
    }
#pragma unroll
    for (int off = 32; off > 0; off >>= 1) v += __shfl_down(v, off, 64);
    __shared__ int ws[4];
    if ((threadIdx.x & 63) == 0) ws[threadIdx.x >> 6] = v;
    __syncthreads();
    if (threadIdx.x == 0) bsum[blockIdx.x] = ws[0] + ws[1] + ws[2] + ws[3];
}

__global__ __launch_bounds__(64)
void scan_bsum_kernel(int* __restrict__ bsum, int* __restrict__ total, int nb) {
    if (threadIdx.x == 0) {
        int run = 0;
        for (int i = 0; i < nb; ++i) { int t = bsum[i]; bsum[i] = run; run += t; }
        *total = run;
    }
}

__global__ __launch_bounds__(256)
void scan_final_kernel(const int* __restrict__ cnt, const int* __restrict__ bsum,
                       int* __restrict__ rowptr, int* __restrict__ wptr, int n) {
    const int base = blockIdx.x * 1024 + threadIdx.x * 4;
    int a0 = 0, a1 = 0, a2 = 0, a3 = 0;
    if (base + 0 < n) a0 = cnt[base + 0];
    if (base + 1 < n) a1 = cnt[base + 1];
    if (base + 2 < n) a2 = cnt[base + 2];
    if (base + 3 < n) a3 = cnt[base + 3];
    const int mysum = a0 + a1 + a2 + a3;
    const int lane = threadIdx.x & 63;
    const int wid  = threadIdx.x >> 6;
    int incl = mysum;
#pragma unroll
    for (int off = 1; off < 64; off <<= 1) {
        int t = __shfl_up(incl, off, 64);
        if (lane >= off) incl += t;
    }
    __shared__ int ws[4];
    if (lane == 63) ws[wid] = incl;
    __syncthreads();
    int woff = 0;
    for (int w = 0; w < wid; ++w) woff += ws[w];
    int pre = bsum[blockIdx.x] + woff + (incl - mysum);
    if (base + 0 < n) { rowptr[base + 0] = pre; wptr[base + 0] = pre; } pre += a0;
    if (base + 1 < n) { rowptr[base + 1] = pre; wptr[base + 1] = pre; } pre += a1;
    if (base + 2 < n) { rowptr[base + 2] = pre; wptr[base + 2] = pre; } pre += a2;
    if (base + 3 < n) { rowptr[base + 3] = pre; wptr[base + 3] = pre; }
}

// ---------------------------------------------------------------------------
// Coarse placement: append packed edge (src | dstlocal<<17) to its
// (bucket, group) sub-region. Groups only spread contention; any mapping ok.
// ---------------------------------------------------------------------------
__global__ __launch_bounds__(THREADS)
void cplace_kernel(const void* __restrict__ ei, const int* __restrict__ flag,
                   int* __restrict__ cptr, unsigned* __restrict__ ebuf, int E) {
    int i = blockIdx.x * THREADS + threadIdx.x;
    if (i >= E) return;
    int s, t;
    load_edge(ei, *flag, E, i, s, t);
    const int g = blockIdx.x & 7;
    const int pos = atomicAdd(&cptr[((t >> NB_SHIFT) << 3) + g], 1);
    ebuf[pos] = (unsigned)s | ((unsigned)(t & (NB - 1)) << 17);
}

// ---------------------------------------------------------------------------
// Fine sort within bucket: one block per bucket. LDS histogram of the 128
// local dst ids -> local exclusive scan -> fine rowptr + placement of esrc
// into the bucket's CONTIGUOUS output region (full-line writes, no global
// write amplification).
// ---------------------------------------------------------------------------
__global__ __launch_bounds__(256)
void finesort_kernel(const int* __restrict__ cbase, const unsigned* __restrict__ ebuf,
                     int* __restrict__ rowptr, int* __restrict__ esrc, int n, int E) {
    __shared__ int hist[NB];
    __shared__ int wp[NB];
    __shared__ int wtot;
    const int b  = blockIdx.x;
    const int e0 = cbase[b << 3];
    const int e1 = cbase[(b + 1) << 3];
    if (threadIdx.x < NB) hist[threadIdx.x] = 0;
    __syncthreads();
    for (int e = e0 + (int)threadIdx.x; e < e1; e += 256)
        atomicAdd(&hist[ebuf[e] >> 17], 1);
    __syncthreads();
    if (threadIdx.x < NB) {
        const int lane = threadIdx.x & 63;
        const int w    = threadIdx.x >> 6;
        const int v    = hist[threadIdx.x];
        int incl = v;
#pragma unroll
        for (int off = 1; off < 64; off <<= 1) {
            int t = __shfl_up(incl, off, 64);
            if (lane >= off) incl += t;
        }
        if (w == 0 && lane == 63) wtot = incl;
        wp[threadIdx.x] = incl - v;      // within-wave exclusive
    }
    __syncthreads();
    if (threadIdx.x < NB) {
        const int excl = wp[threadIdx.x] + ((threadIdx.x >= 64) ? wtot : 0);
        wp[threadIdx.x] = excl;
        const int node = b * NB + (int)threadIdx.x;
        if (node < n) rowptr[node] = e0 + excl;
    }
    if (b == 0 && threadIdx.x == 0) rowptr[n] = E;
    __syncthreads();
    for (int e = e0 + (int)threadIdx.x; e < e1; e += 256) {
        const unsigned wv = ebuf[e];
        const int tl  = (int)(wv >> 17);
        const int pos = e0 + atomicAdd(&wp[tl], 1);
        esrc[pos] = (int)(wv & 0x1FFFFu);
    }
}

// ---------------------------------------------------------------------------
// Dual GEMM: p = x @ Wl, q = x @ Wr (bf16 outputs). Weights in LDS; each
// thread computes R rows x 4 cols of both outputs.
// ---------------------------------------------------------------------------
template <int D_IN, int D_OUT, int R>
__global__ __launch_bounds__(512)
void dual_gemm_kernel(const float* __restrict__ x,
                      const float* __restrict__ Wl, const float* __restrict__ Wr,
                      ushort_t* __restrict__ p, ushort_t* __restrict__ q, int n) {
    constexpr int TPR = D_OUT / 4;
    constexpr int RPB = (512 / TPR) * R;
    __shared__ float sWl[D_IN * D_OUT];
    __shared__ float sWr[D_IN * D_OUT];
    for (int i = threadIdx.x; i < D_IN * D_OUT / 4; i += 512) {
        ((float4*)sWl)[i] = ((const float4*)Wl)[i];
        ((float4*)sWr)[i] = ((const float4*)Wr)[i];
    }
    __syncthreads();
    const int cg   = threadIdx.x % TPR;
    const int rs   = threadIdx.x / TPR;
    const int row0 = blockIdx.x * RPB + rs * R;
    float4 aL[R], aR[R];
#pragma unroll
    for (int r = 0; r < R; ++r) {
        aL[r] = make_float4(0.f, 0.f, 0.f, 0.f);
        aR[r] = make_float4(0.f, 0.f, 0.f, 0.f);
    }
#pragma unroll 4
    for (int k4 = 0; k4 < D_IN / 4; ++k4) {
        float4 xv[R];
#pragma unroll
        for (int r = 0; r < R; ++r) {
            const int row = min(row0 + r, n - 1);
            xv[r] = *(const float4*)(x + (size_t)row * D_IN + 4 * k4);
        }
#pragma unroll
        for (int j = 0; j < 4; ++j) {
            const float4 wl = *(const float4*)(sWl + (4 * k4 + j) * D_OUT + 4 * cg);
            const float4 wr = *(const float4*)(sWr + (4 * k4 + j) * D_OUT + 4 * cg);
#pragma unroll
            for (int r = 0; r < R; ++r) {
                const float a = ((const float*)&xv[r])[j];
                aL[r].x += a * wl.x; aL[r].y += a * wl.y;
                aL[r].z += a * wl.z; aL[r].w += a * wl.w;
                aR[r].x += a * wr.x; aR[r].y += a * wr.y;
                aR[r].z += a * wr.z; aR[r].w += a * wr.w;
            }
        }
    }
#pragma unroll
    for (int r = 0; r < R; ++r) {
        const int row = row0 + r;
        if (row < n) {
            *(ushort4*)(p + (size_t)row * D_OUT + 4 * cg) = f4_to_bf4(aL[r]);
            *(ushort4*)(q + (size_t)row * D_OUT + 4 * cg) = f4_to_bf4(aR[r]);
        }
    }
}

// ---------------------------------------------------------------------------
// Gather-mean + residual + bias + tanh (bf16 in): 16 threads/node, 4-edge
// unroll.  h[v] = tanh(mean_e p[src(e)] + q[v] + b).  Output bf16 or fp32.
// ---------------------------------------------------------------------------
template <bool OUT_BF16>
__global__ __launch_bounds__(THREADS)
void gather_fuse_kernel(const int* __restrict__ rowptr, const int* __restrict__ esrc,
                        const ushort_t* __restrict__ p, const ushort_t* __restrict__ q,
                        const float* __restrict__ bias, void* __restrict__ hout, int n) {
    constexpr int CH  = 16;
    constexpr int NPB = THREADS / CH;
    const int node = blockIdx.x * NPB + (int)(threadIdx.x / CH);
    const int c    = threadIdx.x & (CH - 1);
    if (node >= n) return;
    const int begin = rowptr[node];
    const int end   = rowptr[node + 1];
    float4 acc = make_float4(0.f, 0.f, 0.f, 0.f);
    int e = begin;
    for (; e + 4 <= end; e += 4) {
        const int s0 = esrc[e + 0], s1 = esrc[e + 1], s2 = esrc[e + 2], s3 = esrc[e + 3];
        const float4 v0 = bf4_to_f4(*(const ushort4*)(p + (size_t)s0 * 64 + 4 * c));
        const float4 v1 = bf4_to_f4(*(const ushort4*)(p + (size_t)s1 * 64 + 4 * c));
        const float4 v2 = bf4_to_f4(*(const ushort4*)(p + (size_t)s2 * 64 + 4 * c));
        const float4 v3 = bf4_to_f4(*(const ushort4*)(p + (size_t)s3 * 64 + 4 * c));
        acc.x += v0.x + v1.x + v2.x + v3.x;
        acc.y += v0.y + v1.y + v2.y + v3.y;
        acc.z += v0.z + v1.z + v2.z + v3.z;
        acc.w += v0.w + v1.w + v2.w + v3.w;
    }
    for (; e < end; ++e) {
        const int s = esrc[e];
        const float4 v = bf4_to_f4(*(const ushort4*)(p + (size_t)s * 64 + 4 * c));
        acc.x += v.x; acc.y += v.y; acc.z += v.z; acc.w += v.w;
    }
    const float inv = 1.0f / fmaxf((float)(end - begin), 1.0f);
    const float4 qv = bf4_to_f4(*(const ushort4*)(q + (size_t)node * 64 + 4 * c));
    const float4 bv = *(const float4*)(bias + 4 * c);
    float4 o;
    o.x = tanhf(acc.x * inv + qv.x + bv.x);
    o.y = tanhf(acc.y * inv + qv.y + bv.y);
    o.z = tanhf(acc.z * inv + qv.z + bv.z);
    o.w = tanhf(acc.w * inv + qv.w + bv.w);
    if (OUT_BF16) {
        *(ushort4*)((ushort_t*)hout + (size_t)node * 64 + 4 * c) = f4_to_bf4(o);
    } else {
        *(float4*)((float*)hout + (size_t)node * 64 + 4 * c) = o;
    }
}

// Plain gather-mean (layer 2): agg[v] = mean_e h[src(e)], bf16 in, fp32 out.
__global__ __launch_bounds__(THREADS)
void gather_mean_kernel(const int* __restrict__ rowptr, const int* __restrict__ esrc,
                        const ushort_t* __restrict__ h, float* __restrict__ agg, int n) {
    constexpr int CH  = 16;
    constexpr int NPB = THREADS / CH;
    const int node = blockIdx.x * NPB + (int)(threadIdx.x / CH);
    const int c    = threadIdx.x & (CH - 1);
    if (node >= n) return;
    const int begin = rowptr[node];
    const int end   = rowptr[node + 1];
    float4 acc = make_float4(0.f, 0.f, 0.f, 0.f);
    int e = begin;
    for (; e + 4 <= end; e += 4) {
        const int s0 = esrc[e + 0], s1 = esrc[e + 1], s2 = esrc[e + 2], s3 = esrc[e + 3];
        const float4 v0 = bf4_to_f4(*(const ushort4*)(h + (size_t)s0 * 64 + 4 * c));
        const float4 v1 = bf4_to_f4(*(const ushort4*)(h + (size_t)s1 * 64 + 4 * c));
        const float4 v2 = bf4_to_f4(*(const ushort4*)(h + (size_t)s2 * 64 + 4 * c));
        const float4 v3 = bf4_to_f4(*(const ushort4*)(h + (size_t)s3 * 64 + 4 * c));
        acc.x += v0.x + v1.x + v2.x + v3.x;
        acc.y += v0.y + v1.y + v2.y + v3.y;
        acc.z += v0.z + v1.z + v2.z + v3.z;
        acc.w += v0.w + v1.w + v2.w + v3.w;
    }
    for (; e < end; ++e) {
        const int s = esrc[e];
        const float4 v = bf4_to_f4(*(const ushort4*)(h + (size_t)s * 64 + 4 * c));
        acc.x += v.x; acc.y += v.y; acc.z += v.z; acc.w += v.w;
    }
    const float inv = 1.0f / fmaxf((float)(end - begin), 1.0f);
    float4 o = make_float4(acc.x * inv, acc.y * inv, acc.z * inv, acc.w * inv);
    *(float4*)(agg + (size_t)node * 64 + 4 * c) = o;
}

// ---------------------------------------------------------------------------
// Fused layer 2: hout = tanh(agg @ Wl + hin @ Wr + b), 64 -> 128.
// agg fp32, hin bf16, out fp32.
// ---------------------------------------------------------------------------
template <int D_IN, int D_OUT, int R>
__global__ __launch_bounds__(512)
void layer_kernel(const float* __restrict__ agg, const ushort_t* __restrict__ hin,
                  const float* __restrict__ Wl, const float* __restrict__ Wr,
                  const float* __restrict__ bias,
                  float* __restrict__ hout, int n) {
    constexpr int TPR = D_OUT / 4;
    constexpr int RPB = (512 / TPR) * R;
    __shared__ float sWl[D_IN * D_OUT];
    __shared__ float sWr[D_IN * D_OUT];
    __shared__ float sb[D_OUT];
    for (int i = threadIdx.x; i < D_IN * D_OUT / 4; i += 512) {
        ((float4*)sWl)[i] = ((const float4*)Wl)[i];
        ((float4*)sWr)[i] = ((const float4*)Wr)[i];
    }
    if (threadIdx.x < D_OUT) sb[threadIdx.x] = bias[threadIdx.x];
    __syncthreads();
    const int cg   = threadIdx.x % TPR;
    const int rs   = threadIdx.x / TPR;
    const int row0 = blockIdx.x * RPB + rs * R;
    float4 acc[R];
#pragma unroll
    for (int r = 0; r < R; ++r) acc[r] = make_float4(0.f, 0.f, 0.f, 0.f);
#pragma unroll 4
    for (int k4 = 0; k4 < D_IN / 4; ++k4) {
        float4 av[R], hv[R];
#pragma unroll
        for (int r = 0; r < R; ++r) {
            const int row = min(row0 + r, n - 1);
            av[r] = *(const float4*)(agg + (size_t)row * D_IN + 4 * k4);
            hv[r] = bf4_to_f4(*(const ushort4*)(hin + (size_t)row * D_IN + 4 * k4));
        }
#pragma unroll
        for (int j = 0; j < 4; ++j) {
            const float4 wl = *(const float4*)(sWl + (4 * k4 + j) * D_OUT + 4 * cg);
            const float4 wr = *(const float4*)(sWr + (4 * k4 + j) * D_OUT + 4 * cg);
#pragma unroll
            for (int r = 0; r < R; ++r) {
                const float a = ((const float*)&av[r])[j];
                const float b = ((const float*)&hv[r])[j];
                acc[r].x += a * wl.x + b * wr.x;
                acc[r].y += a * wl.y + b * wr.y;
                acc[r].z += a * wl.z + b * wr.z;
                acc[r].w += a * wl.w + b * wr.w;
            }
        }
    }
#pragma unroll
    for (int r = 0; r < R; ++r) {
        const int row = row0 + r;
        if (row < n) {
            float4 o;
            o.x = tanhf(acc[r].x + sb[4 * cg + 0]);
            o.y = tanhf(acc[r].y + sb[4 * cg + 1]);
            o.z = tanhf(acc[r].z + sb[4 * cg + 2]);
            o.w = tanhf(acc[r].w + sb[4 * cg + 3]);
            *(float4*)(hout + (size_t)row * D_OUT + 4 * cg) = o;
        }
    }
}

// ---------------------------------------------------------------------------
// Head: out = h @ Wlin + blin   ([n,64] x [64,10]), fp32.
// ---------------------------------------------------------------------------
__global__ __launch_bounds__(THREADS)
void head_kernel(const float* __restrict__ h, const float* __restrict__ W,
                 const float* __restrict__ bias, float* __restrict__ out, int n) {
    __shared__ float sW[64 * 10];
    __shared__ float sb[10];
    for (int i = threadIdx.x; i < 640; i += THREADS) sW[i] = W[i];
    if (threadIdx.x < 10) sb[threadIdx.x] = bias[threadIdx.x];
    __syncthreads();
    int idx = blockIdx.x * THREADS + threadIdx.x;
    if (idx >= n * 10) return;
    int row = idx / 10;
    int col = idx - row * 10;
    const float* __restrict__ hr = h + (size_t)row * 64;
    float acc = sb[col];
#pragma unroll 16
    for (int k = 0; k < 64; ++k) acc += hr[k] * sW[k * 10 + col];
    out[idx] = acc;
}

extern "C" void kernel_launch(void* const* d_in, const int* in_sizes, int n_in,
                              void* d_out, int out_size, void* d_ws, size_t ws_size,
                              hipStream_t stream) {
    const float* x    = (const float*)d_in[0];
    const void*  ei   = d_in[1];
    const float* W1l  = (const float*)d_in[2];
    const float* W1r  = (const float*)d_in[3];
    const float* b1   = (const float*)d_in[4];
    const float* W2l  = (const float*)d_in[5];
    const float* W2r  = (const float*)d_in[6];
    const float* b2   = (const float*)d_in[7];
    const float* W3l  = (const float*)d_in[8];
    const float* W3r  = (const float*)d_in[9];
    const float* b3   = (const float*)d_in[10];
    const float* Wlin = (const float*)d_in[11];
    const float* blin = (const float*)d_in[12];
    float* out = (float*)d_out;

    const int n = in_sizes[0] / 128;   // 100000
    const int E = in_sizes[1] / 2;     // 1600000
    const int B = (n + NB - 1) / NB;   // buckets (782)
    const int C = B * 8;               // coarse counters

    // --- workspace carve-up (~128 MB) ---
    char* ws = (char*)d_ws;
    size_t off = 0;
    auto carve = [&](size_t bytes) {
        void* p = ws + off;
        off += (bytes + 255) & ~(size_t)255;
        return p;
    };
    int*      flag   = (int*)     carve(256);
    int*      cc     = (int*)     carve((size_t)C * 4);
    int*      cbase  = (int*)     carve((size_t)(C + 1) * 4);
    int*      cptr   = (int*)     carve((size_t)C * 4);
    int*      bsum   = (int*)     carve(4096);
    unsigned* ebuf   = (unsigned*)carve((size_t)E * 4);
    int*      rowptr = (int*)     carve((size_t)(n + 1) * 4);
    int*      esrc   = (int*)     carve((size_t)E * 4);
    float*    agg    = (float*)   carve((size_t)n * 64 * 4);   // overlays p,q
    ushort_t* p      = (ushort_t*)agg;                          // [n*64] bf16
    ushort_t* q      = (ushort_t*)agg + (size_t)n * 64;         // [n*64] bf16
    ushort_t* h1     = (ushort_t*)carve((size_t)n * 64 * 2);    // bf16
    float*    h2     = (float*)   carve((size_t)n * 128 * 4);
    float*    h3     = (float*)   carve((size_t)n * 64 * 4);
    (void)ws_size;

    const int eblocks = (E + THREADS - 1) / THREADS;
    const int cscan   = (C + 1023) / 1024;

    // --- two-level edge sort (once; graph shared by all layers) ---
    detect_kernel<<<1, 64, 0, stream>>>((const unsigned*)ei, flag);
    hipMemsetAsync(cc, 0, (size_t)C * 4, stream);
    ccount_kernel<<<eblocks, THREADS, 0, stream>>>(ei, flag, cc, E);
    scan_partial_kernel<<<cscan, 256, 0, stream>>>(cc, bsum, C);
    scan_bsum_kernel<<<1, 64, 0, stream>>>(bsum, cbase + C, cscan);
    scan_final_kernel<<<cscan, 256, 0, stream>>>(cc, bsum, cbase, cptr, C);
    cplace_kernel<<<eblocks, THREADS, 0, stream>>>(ei, flag, cptr, ebuf, E);
    finesort_kernel<<<B, 256, 0, stream>>>(cbase, ebuf, rowptr, esrc, n, E);

    // --- layer 1: project-then-aggregate (mean(x)@W = mean(x@W)) ---
    dual_gemm_kernel<128, 64, 2><<<(n + 63) / 64, 512, 0, stream>>>(
        x, W1l, W1r, p, q, n);
    gather_fuse_kernel<true><<<(n + 15) / 16, THREADS, 0, stream>>>(
        rowptr, esrc, p, q, b1, h1, n);

    // --- layer 2: aggregate-then-project (64 -> 128) ---
    gather_mean_kernel<<<(n + 15) / 16, THREADS, 0, stream>>>(
        rowptr, esrc, h1, agg, n);
    layer_kernel<64, 128, 2><<<(n + 31) / 32, 512, 0, stream>>>(
        agg, h1, W2l, W2r, b2, h2, n);

    // --- layer 3: project-then-aggregate ---
    dual_gemm_kernel<128, 64, 2><<<(n + 63) / 64, 512, 0, stream>>>(
        h2, W3l, W3r, p, q, n);
    gather_fuse_kernel<false><<<(n + 15) / 16, THREADS, 0, stream>>>(
        rowptr, esrc, p, q, b3, h3, n);

    // --- head ---
    head_kernel<<<(n * 10 + THREADS - 1) / THREADS, THREADS, 0, stream>>>(
        h3, Wlin, blin, out, n);
}

// Round 6
// 372.425 us; speedup vs baseline: 6.5003x; 1.4110x over previous
//
#include <hip/hip_runtime.h>

#define THREADS 256
#define NB_SHIFT 7              // 128 nodes per bucket
#define NB 128
#define WT_LD 136               // padded K stride for packed weights (x8 aligned)

typedef unsigned short ushort_t;
typedef __attribute__((ext_vector_type(8))) short bf16x8;
typedef __attribute__((ext_vector_type(4))) float f32x4;

__device__ __forceinline__ unsigned short f2bf(float f) {
    unsigned u = __float_as_uint(f);
    u += 0x7fff + ((u >> 16) & 1);   // round-to-nearest-even
    return (unsigned short)(u >> 16);
}
__device__ __forceinline__ float bf2f(unsigned short s) {
    return __uint_as_float((unsigned)s << 16);
}
__device__ __forceinline__ float4 bf4_to_f4(ushort4 u) {
    return make_float4(bf2f(u.x), bf2f(u.y), bf2f(u.z), bf2f(u.w));
}
__device__ __forceinline__ ushort4 f4_to_bf4(float4 v) {
    ushort4 o;
    o.x = f2bf(v.x); o.y = f2bf(v.y); o.z = f2bf(v.z); o.w = f2bf(v.w);
    return o;
}

// ---------------------------------------------------------------------------
// Edge-index dtype detection: little-endian int64 values < 2^31 have all-zero
// odd 32-bit words. flag=1 -> int64 layout, flag=0 -> int32 layout.
// ---------------------------------------------------------------------------
__global__ __launch_bounds__(64)
void detect_kernel(const unsigned* __restrict__ ei_words, int* __restrict__ flag) {
    if (threadIdx.x == 0 && blockIdx.x == 0) {
        int allzero = 1;
        for (int i = 0; i < 64; ++i) {
            if (ei_words[2 * i + 1] != 0u) { allzero = 0; break; }
        }
        *flag = allzero;
    }
}

__device__ __forceinline__ void load_edge(const void* ei, int is64, int E, int i,
                                          int& s, int& t) {
    if (is64) {
        const long long* p = (const long long*)ei;
        s = (int)p[i];
        t = (int)p[E + i];
    } else {
        const int* p = (const int*)ei;
        s = p[i];
        t = p[E + i];
    }
}

// ---------------------------------------------------------------------------
// Coarse histogram: counts per (bucket = dst>>7, group = blockIdx&7).
// ---------------------------------------------------------------------------
__global__ __launch_bounds__(THREADS)
void ccount_kernel(const void* __restrict__ ei, const int* __restrict__ flag,
                   int* __restrict__ cc, int E) {
    int i = blockIdx.x * THREADS + threadIdx.x;
    if (i >= E) return;
    int s, t;
    load_edge(ei, *flag, E, i, s, t);
    (void)s;
    const int g = blockIdx.x & 7;
    atomicAdd(&cc[((t >> NB_SHIFT) << 3) + g], 1);
}

// ---------------------------------------------------------------------------
// Three-kernel exclusive scan over the C=B*8 coarse counters.
// ---------------------------------------------------------------------------
__global__ __launch_bounds__(256)
void scan_partial_kernel(const int* __restrict__ cnt, int* __restrict__ bsum, int n) {
    const int base = blockIdx.x * 1024;
    int v = 0;
    for (int i = threadIdx.x; i < 1024; i += 256) {
        const int idx = base + i;
        v += (idx < n) ? cnt[idx] : 0;
    }
#pragma unroll
    for (int off = 32; off > 0; off >>= 1) v += __shfl_down(v, off, 64);
    __shared__ int ws[4];
    if ((threadIdx.x & 63) == 0) ws[threadIdx.x >> 6] = v;
    __syncthreads();
    if (threadIdx.x == 0) bsum[blockIdx.x] = ws[0] + ws[1] + ws[2] + ws[3];
}

__global__ __launch_bounds__(64)
void scan_bsum_kernel(int* __restrict__ bsum, int* __restrict__ total, int nb) {
    if (threadIdx.x == 0) {
        int run = 0;
        for (int i = 0; i < nb; ++i) { int t = bsum[i]; bsum[i] = run; run += t; }
        *total = run;
    }
}

__global__ __launch_bounds__(256)
void scan_final_kernel(const int* __restrict__ cnt, const int* __restrict__ bsum,
                       int* __restrict__ rowptr, int* __restrict__ wptr, int n) {
    const int base = blockIdx.x * 1024 + threadIdx.x * 4;
    int a0 = 0, a1 = 0, a2 = 0, a3 = 0;
    if (base + 0 < n) a0 = cnt[base + 0];
    if (base + 1 < n) a1 = cnt[base + 1];
    if (base + 2 < n) a2 = cnt[base + 2];
    if (base + 3 < n) a3 = cnt[base + 3];
    const int mysum = a0 + a1 + a2 + a3;
    const int lane = threadIdx.x & 63;
    const int wid  = threadIdx.x >> 6;
    int incl = mysum;
#pragma unroll
    for (int off = 1; off < 64; off <<= 1) {
        int t = __shfl_up(incl, off, 64);
        if (lane >= off) incl += t;
    }
    __shared__ int ws[4];
    if (lane == 63) ws[wid] = incl;
    __syncthreads();
    int woff = 0;
    for (int w = 0; w < wid; ++w) woff += ws[w];
    int pre = bsum[blockIdx.x] + woff + (incl - mysum);
    if (base + 0 < n) { rowptr[base + 0] = pre; wptr[base + 0] = pre; } pre += a0;
    if (base + 1 < n) { rowptr[base + 1] = pre; wptr[base + 1] = pre; } pre += a1;
    if (base + 2 < n) { rowptr[base + 2] = pre; wptr[base + 2] = pre; } pre += a2;
    if (base + 3 < n) { rowptr[base + 3] = pre; wptr[base + 3] = pre; }
}

// ---------------------------------------------------------------------------
// Coarse placement: append packed edge (src | dstlocal<<17).
// ---------------------------------------------------------------------------
__global__ __launch_bounds__(THREADS)
void cplace_kernel(const void* __restrict__ ei, const int* __restrict__ flag,
                   int* __restrict__ cptr, unsigned* __restrict__ ebuf, int E) {
    int i = blockIdx.x * THREADS + threadIdx.x;
    if (i >= E) return;
    int s, t;
    load_edge(ei, *flag, E, i, s, t);
    const int g = blockIdx.x & 7;
    const int pos = atomicAdd(&cptr[((t >> NB_SHIFT) << 3) + g], 1);
    ebuf[pos] = (unsigned)s | ((unsigned)(t & (NB - 1)) << 17);
}

// ---------------------------------------------------------------------------
// Fine sort within bucket -> rowptr + contiguous esrc region per bucket.
// ---------------------------------------------------------------------------
__global__ __launch_bounds__(256)
void finesort_kernel(const int* __restrict__ cbase, const unsigned* __restrict__ ebuf,
                     int* __restrict__ rowptr, int* __restrict__ esrc, int n, int E) {
    __shared__ int hist[NB];
    __shared__ int wp[NB];
    __shared__ int wtot;
    const int b  = blockIdx.x;
    const int e0 = cbase[b << 3];
    const int e1 = cbase[(b + 1) << 3];
    if (threadIdx.x < NB) hist[threadIdx.x] = 0;
    __syncthreads();
    for (int e = e0 + (int)threadIdx.x; e < e1; e += 256)
        atomicAdd(&hist[ebuf[e] >> 17], 1);
    __syncthreads();
    if (threadIdx.x < NB) {
        const int lane = threadIdx.x & 63;
        const int w    = threadIdx.x >> 6;
        const int v    = hist[threadIdx.x];
        int incl = v;
#pragma unroll
        for (int off = 1; off < 64; off <<= 1) {
            int t = __shfl_up(incl, off, 64);
            if (lane >= off) incl += t;
        }
        if (w == 0 && lane == 63) wtot = incl;
        wp[threadIdx.x] = incl - v;
    }
    __syncthreads();
    if (threadIdx.x < NB) {
        const int excl = wp[threadIdx.x] + ((threadIdx.x >= 64) ? wtot : 0);
        wp[threadIdx.x] = excl;
        const int node = b * NB + (int)threadIdx.x;
        if (node < n) rowptr[node] = e0 + excl;
    }
    if (b == 0 && threadIdx.x == 0) rowptr[n] = E;
    __syncthreads();
    for (int e = e0 + (int)threadIdx.x; e < e1; e += 256) {
        const unsigned wv = ebuf[e];
        const int tl  = (int)(wv >> 17);
        const int pos = e0 + atomicAdd(&wp[tl], 1);
        esrc[pos] = (int)(wv & 0x1FFFFu);
    }
}

// ---------------------------------------------------------------------------
// Weight packing: WT[c][k] = Wcat[k][c] as bf16, row stride WT_LD.
// dual: Wcat[k][c] = c<64 ? Wl[k][c] : Wr[k][c-64]   (two 128x64, concat N)
// stack: Wcat[k][c] = k<64 ? Wl[k][c] : Wr[k-64][c]  (two 64x128, concat K)
// ---------------------------------------------------------------------------
__global__ __launch_bounds__(256)
void pack_dual_kernel(const float* __restrict__ Wl, const float* __restrict__ Wr,
                      ushort_t* __restrict__ WT) {
    int i = blockIdx.x * 256 + threadIdx.x;
    if (i >= 128 * 128) return;
    int k = i >> 7, c = i & 127;
    float v = (c < 64) ? Wl[k * 64 + c] : Wr[k * 64 + (c - 64)];
    WT[c * WT_LD + k] = f2bf(v);
}
__global__ __launch_bounds__(256)
void pack_stack_kernel(const float* __restrict__ Wl, const float* __restrict__ Wr,
                       ushort_t* __restrict__ WT) {
    int i = blockIdx.x * 256 + threadIdx.x;
    if (i >= 128 * 128) return;
    int k = i >> 7, c = i & 127;
    float v = (k < 64) ? Wl[k * 128 + c] : Wr[(k - 64) * 128 + c];
    WT[c * WT_LD + k] = f2bf(v);
}

// ---------------------------------------------------------------------------
// MFMA GEMM: C[n][128] (bf16) = A[n][128] @ W[128][128]  (+bias, tanh opt).
// W pre-packed transposed bf16 [128][WT_LD], staged in LDS.
// Block: 256 thr = 4 waves; wave owns 16 rows x 128 cols (8 col-tiles x 4 K-mfma).
// mfma_f32_16x16x32_bf16: A row = lane&15, B col = lane&15, kgroup = lane>>4;
// C/D: col = lane&15, row = (lane>>4)*4 + reg  [verified m89/m91].
// ---------------------------------------------------------------------------
template <bool A_FP32, bool TANH_BIAS>
__global__ __launch_bounds__(256)
void mfma_gemm_kernel(const void* __restrict__ Av, const ushort_t* __restrict__ WT,
                      const float* __restrict__ bias, ushort_t* __restrict__ C, int n) {
    __shared__ ushort_t sW[128 * WT_LD];
    {
        const uint4* gsrc = (const uint4*)WT;
        uint4* ldst = (uint4*)sW;
        for (int i = threadIdx.x; i < 128 * WT_LD * 2 / 16; i += 256) ldst[i] = gsrc[i];
    }
    __syncthreads();
    const int lane = threadIdx.x & 63;
    const int wave = threadIdx.x >> 6;
    const int row0 = blockIdx.x * 64 + wave * 16;
    const int rA   = min(row0 + (lane & 15), n - 1);
    const int kg   = lane >> 4;       // 0..3

    bf16x8 a[4];
    if (A_FP32) {
        const float* A = (const float*)Av;
#pragma unroll
        for (int t = 0; t < 4; ++t) {
            const float4 lo = *(const float4*)(A + (size_t)rA * 128 + t * 32 + kg * 8);
            const float4 hi = *(const float4*)(A + (size_t)rA * 128 + t * 32 + kg * 8 + 4);
            const ushort4 u0 = f4_to_bf4(lo), u1 = f4_to_bf4(hi);
            bf16x8 av;
            av[0] = (short)u0.x; av[1] = (short)u0.y; av[2] = (short)u0.z; av[3] = (short)u0.w;
            av[4] = (short)u1.x; av[5] = (short)u1.y; av[6] = (short)u1.z; av[7] = (short)u1.w;
            a[t] = av;
        }
    } else {
        const ushort_t* A = (const ushort_t*)Av;
#pragma unroll
        for (int t = 0; t < 4; ++t)
            a[t] = *(const bf16x8*)(A + (size_t)rA * 128 + t * 32 + kg * 8);
    }

    f32x4 acc[8];
#pragma unroll
    for (int ct = 0; ct < 8; ++ct) acc[ct] = (f32x4)(0.f);

#pragma unroll
    for (int ct = 0; ct < 8; ++ct) {
        const int c0 = ct * 16 + (lane & 15);
#pragma unroll
        for (int t = 0; t < 4; ++t) {
            const bf16x8 b = *(const bf16x8*)(sW + (size_t)c0 * WT_LD + t * 32 + kg * 8);
            acc[ct] = __builtin_amdgcn_mfma_f32_16x16x32_bf16(a[t], b, acc[ct], 0, 0, 0);
        }
    }

    const int orow = row0 + kg * 4;
#pragma unroll
    for (int ct = 0; ct < 8; ++ct) {
        const int col = ct * 16 + (lane & 15);
        const float badd = TANH_BIAS ? bias[col] : 0.f;
#pragma unroll
        for (int i = 0; i < 4; ++i) {
            const int r = orow + i;
            if (r < n) {
                float v = acc[ct][i];
                if (TANH_BIAS) v = tanhf(v + badd);
                C[(size_t)r * 128 + col] = f2bf(v);
            }
        }
    }
}

// ---------------------------------------------------------------------------
// Gather-mean + residual + bias + tanh over concat buffer pq[n][128]
// (p = cols 0..63 by src, q = cols 64..127 by node).
// OUTMODE 0: write into ah[node][64+4c] (stride 128). OUTMODE 1: h[node][4c] (stride 64).
// ---------------------------------------------------------------------------
template <int OUTMODE>
__global__ __launch_bounds__(THREADS)
void gather_fuse_kernel(const int* __restrict__ rowptr, const int* __restrict__ esrc,
                        const ushort_t* __restrict__ pq, const float* __restrict__ bias,
                        ushort_t* __restrict__ hout, int n) {
    constexpr int CH  = 16;
    constexpr int NPB = THREADS / CH;
    const int node = blockIdx.x * NPB + (int)(threadIdx.x / CH);
    const int c    = threadIdx.x & (CH - 1);
    if (node >= n) return;
    const int begin = rowptr[node];
    const int end   = rowptr[node + 1];
    float4 acc = make_float4(0.f, 0.f, 0.f, 0.f);
    int e = begin;
    for (; e + 4 <= end; e += 4) {
        const int s0 = esrc[e + 0], s1 = esrc[e + 1], s2 = esrc[e + 2], s3 = esrc[e + 3];
        const float4 v0 = bf4_to_f4(*(const ushort4*)(pq + (size_t)s0 * 128 + 4 * c));
        const float4 v1 = bf4_to_f4(*(const ushort4*)(pq + (size_t)s1 * 128 + 4 * c));
        const float4 v2 = bf4_to_f4(*(const ushort4*)(pq + (size_t)s2 * 128 + 4 * c));
        const float4 v3 = bf4_to_f4(*(const ushort4*)(pq + (size_t)s3 * 128 + 4 * c));
        acc.x += v0.x + v1.x + v2.x + v3.x;
        acc.y += v0.y + v1.y + v2.y + v3.y;
        acc.z += v0.z + v1.z + v2.z + v3.z;
        acc.w += v0.w + v1.w + v2.w + v3.w;
    }
    for (; e < end; ++e) {
        const int s = esrc[e];
        const float4 v = bf4_to_f4(*(const ushort4*)(pq + (size_t)s * 128 + 4 * c));
        acc.x += v.x; acc.y += v.y; acc.z += v.z; acc.w += v.w;
    }
    const float inv = 1.0f / fmaxf((float)(end - begin), 1.0f);
    const float4 qv = bf4_to_f4(*(const ushort4*)(pq + (size_t)node * 128 + 64 + 4 * c));
    const float4 bv = *(const float4*)(bias + 4 * c);
    float4 o;
    o.x = tanhf(acc.x * inv + qv.x + bv.x);
    o.y = tanhf(acc.y * inv + qv.y + bv.y);
    o.z = tanhf(acc.z * inv + qv.z + bv.z);
    o.w = tanhf(acc.w * inv + qv.w + bv.w);
    if (OUTMODE == 0) {
        *(ushort4*)(hout + (size_t)node * 128 + 64 + 4 * c) = f4_to_bf4(o);
    } else {
        *(ushort4*)(hout + (size_t)node * 64 + 4 * c) = f4_to_bf4(o);
    }
}

// ---------------------------------------------------------------------------
// gather-mean into ah cols 0..63 reading ah cols 64..127 (disjoint ranges).
// ---------------------------------------------------------------------------
__global__ __launch_bounds__(THREADS)
void gather_mean_kernel(const int* __restrict__ rowptr, const int* __restrict__ esrc,
                        ushort_t* __restrict__ ah, int n) {
    constexpr int CH  = 16;
    constexpr int NPB = THREADS / CH;
    const int node = blockIdx.x * NPB + (int)(threadIdx.x / CH);
    const int c    = threadIdx.x & (CH - 1);
    if (node >= n) return;
    const int begin = rowptr[node];
    const int end   = rowptr[node + 1];
    float4 acc = make_float4(0.f, 0.f, 0.f, 0.f);
    int e = begin;
    for (; e + 4 <= end; e += 4) {
        const int s0 = esrc[e + 0], s1 = esrc[e + 1], s2 = esrc[e + 2], s3 = esrc[e + 3];
        const float4 v0 = bf4_to_f4(*(const ushort4*)(ah + (size_t)s0 * 128 + 64 + 4 * c));
        const float4 v1 = bf4_to_f4(*(const ushort4*)(ah + (size_t)s1 * 128 + 64 + 4 * c));
        const float4 v2 = bf4_to_f4(*(const ushort4*)(ah + (size_t)s2 * 128 + 64 + 4 * c));
        const float4 v3 = bf4_to_f4(*(const ushort4*)(ah + (size_t)s3 * 128 + 64 + 4 * c));
        acc.x += v0.x + v1.x + v2.x + v3.x;
        acc.y += v0.y + v1.y + v2.y + v3.y;
        acc.z += v0.z + v1.z + v2.z + v3.z;
        acc.w += v0.w + v1.w + v2.w + v3.w;
    }
    for (; e < end; ++e) {
        const int s = esrc[e];
        const float4 v = bf4_to_f4(*(const ushort4*)(ah + (size_t)s * 128 + 64 + 4 * c));
        acc.x += v.x; acc.y += v.y; acc.z += v.z; acc.w += v.w;
    }
    const float inv = 1.0f / fmaxf((float)(end - begin), 1.0f);
    ushort4 o = f4_to_bf4(make_float4(acc.x * inv, acc.y * inv, acc.z * inv, acc.w * inv));
    *(ushort4*)(ah + (size_t)node * 128 + 4 * c) = o;
}

// ---------------------------------------------------------------------------
// Head: out = h @ Wlin + blin   ([n,64] bf16 x [64,10] fp32) -> fp32.
// ---------------------------------------------------------------------------
__global__ __launch_bounds__(THREADS)
void head_kernel(const ushort_t* __restrict__ h, const float* __restrict__ W,
                 const float* __restrict__ bias, float* __restrict__ out, int n) {
    __shared__ float sW[64 * 10];
    __shared__ float sb[10];
    for (int i = threadIdx.x; i < 640; i += THREADS) sW[i] = W[i];
    if (threadIdx.x < 10) sb[threadIdx.x] = bias[threadIdx.x];
    __syncthreads();
    int idx = blockIdx.x * THREADS + threadIdx.x;
    if (idx >= n * 10) return;
    int row = idx / 10;
    int col = idx - row * 10;
    const ushort_t* __restrict__ hr = h + (size_t)row * 64;
    float acc = sb[col];
#pragma unroll 16
    for (int k = 0; k < 64; ++k) acc += bf2f(hr[k]) * sW[k * 10 + col];
    out[idx] = acc;
}

extern "C" void kernel_launch(void* const* d_in, const int* in_sizes, int n_in,
                              void* d_out, int out_size, void* d_ws, size_t ws_size,
                              hipStream_t stream) {
    const float* x    = (const float*)d_in[0];
    const void*  ei   = d_in[1];
    const float* W1l  = (const float*)d_in[2];
    const float* W1r  = (const float*)d_in[3];
    const float* b1   = (const float*)d_in[4];
    const float* W2l  = (const float*)d_in[5];
    const float* W2r  = (const float*)d_in[6];
    const float* b2   = (const float*)d_in[7];
    const float* W3l  = (const float*)d_in[8];
    const float* W3r  = (const float*)d_in[9];
    const float* b3   = (const float*)d_in[10];
    const float* Wlin = (const float*)d_in[11];
    const float* blin = (const float*)d_in[12];
    float* out = (float*)d_out;

    const int n = in_sizes[0] / 128;   // 100000
    const int E = in_sizes[1] / 2;     // 1600000
    const int B = (n + NB - 1) / NB;   // buckets
    const int C = B * 8;               // coarse counters

    // --- workspace carve-up (~103 MB) ---
    char* ws = (char*)d_ws;
    size_t off = 0;
    auto carve = [&](size_t bytes) {
        void* p = ws + off;
        off += (bytes + 255) & ~(size_t)255;
        return p;
    };
    int*      flag   = (int*)     carve(256);
    int*      cc     = (int*)     carve((size_t)C * 4);
    int*      cbase  = (int*)     carve((size_t)(C + 1) * 4);
    int*      cptr   = (int*)     carve((size_t)C * 4);
    int*      bsum   = (int*)     carve(4096);
    unsigned* ebuf   = (unsigned*)carve((size_t)E * 4);
    int*      rowptr = (int*)     carve((size_t)(n + 1) * 4);
    int*      esrc   = (int*)     carve((size_t)E * 4);
    ushort_t* WT1    = (ushort_t*)carve((size_t)128 * WT_LD * 2);
    ushort_t* WT2    = (ushort_t*)carve((size_t)128 * WT_LD * 2);
    ushort_t* WT3    = (ushort_t*)carve((size_t)128 * WT_LD * 2);
    ushort_t* pq     = (ushort_t*)carve((size_t)n * 128 * 2);  // GEMM1/3 out
    ushort_t* ah     = (ushort_t*)carve((size_t)n * 128 * 2);  // [agg|h1]
    ushort_t* h2     = (ushort_t*)carve((size_t)n * 128 * 2);
    ushort_t* h3     = (ushort_t*)carve((size_t)n * 64 * 2);
    (void)ws_size;

    const int eblocks = (E + THREADS - 1) / THREADS;
    const int cscan   = (C + 1023) / 1024;
    const int gblocks = (n + 63) / 64;

    // --- weight packing (tiny) ---
    pack_dual_kernel <<<64, 256, 0, stream>>>(W1l, W1r, WT1);
    pack_stack_kernel<<<64, 256, 0, stream>>>(W2l, W2r, WT2);
    pack_dual_kernel <<<64, 256, 0, stream>>>(W3l, W3r, WT3);

    // --- two-level edge sort (once; graph shared by all layers) ---
    detect_kernel<<<1, 64, 0, stream>>>((const unsigned*)ei, flag);
    hipMemsetAsync(cc, 0, (size_t)C * 4, stream);
    ccount_kernel<<<eblocks, THREADS, 0, stream>>>(ei, flag, cc, E);
    scan_partial_kernel<<<cscan, 256, 0, stream>>>(cc, bsum, C);
    scan_bsum_kernel<<<1, 64, 0, stream>>>(bsum, cbase + C, cscan);
    scan_final_kernel<<<cscan, 256, 0, stream>>>(cc, bsum, cbase, cptr, C);
    cplace_kernel<<<eblocks, THREADS, 0, stream>>>(ei, flag, cptr, ebuf, E);
    finesort_kernel<<<B, 256, 0, stream>>>(cbase, ebuf, rowptr, esrc, n, E);

    // --- layer 1: pq = x @ [W1l|W1r]; h1 = tanh(mean(p) + q + b1) -> ah[:,64:] ---
    mfma_gemm_kernel<true, false><<<gblocks, 256, 0, stream>>>(x, WT1, nullptr, pq, n);
    gather_fuse_kernel<0><<<(n + 15) / 16, THREADS, 0, stream>>>(
        rowptr, esrc, pq, b1, ah, n);

    // --- layer 2: ah[:,0:64] = mean(h1); h2 = tanh(ah @ [W2l;W2r] + b2) ---
    gather_mean_kernel<<<(n + 15) / 16, THREADS, 0, stream>>>(rowptr, esrc, ah, n);
    mfma_gemm_kernel<false, true><<<gblocks, 256, 0, stream>>>(ah, WT2, b2, h2, n);

    // --- layer 3: pq = h2 @ [W3l|W3r]; h3 = tanh(mean(p) + q + b3) ---
    mfma_gemm_kernel<false, false><<<gblocks, 256, 0, stream>>>(h2, WT3, nullptr, pq, n);
    gather_fuse_kernel<1><<<(n + 15) / 16, THREADS, 0, stream>>>(
        rowptr, esrc, pq, b3, h3, n);

    // --- head ---
    head_kernel<<<(n * 10 + THREADS - 1) / THREADS, THREADS, 0, stream>>>(
        h3, Wlin, blin, out, n);
}

// Round 7
// 258.362 us; speedup vs baseline: 9.3701x; 1.4415x over previous
//
#include <hip/hip_runtime.h>

#define THREADS 256
#define NB 256                  // nodes per bucket
#define NB_SHIFT 8
#define TILE_E 4096             // edges per sort tile
#define EPT 16                  // edges per thread in tilesort (TILE_E/256)
#define BMAXPAD 512             // padded bucket-hist size in tilesort
#define WT_LD 136               // padded K stride for packed weights

typedef unsigned short ushort_t;
typedef __attribute__((ext_vector_type(8))) short bf16x8;
typedef __attribute__((ext_vector_type(4))) float f32x4;

__device__ __forceinline__ unsigned short f2bf(float f) {
    unsigned u = __float_as_uint(f);
    u += 0x7fff + ((u >> 16) & 1);   // round-to-nearest-even
    return (unsigned short)(u >> 16);
}
__device__ __forceinline__ float bf2f(unsigned short s) {
    return __uint_as_float((unsigned)s << 16);
}
__device__ __forceinline__ float4 bf4_to_f4(ushort4 u) {
    return make_float4(bf2f(u.x), bf2f(u.y), bf2f(u.z), bf2f(u.w));
}
__device__ __forceinline__ ushort4 f4_to_bf4(float4 v) {
    ushort4 o;
    o.x = f2bf(v.x); o.y = f2bf(v.y); o.z = f2bf(v.z); o.w = f2bf(v.w);
    return o;
}

// ---------------------------------------------------------------------------
// Edge-index dtype detection: little-endian int64 values < 2^31 have all-zero
// odd 32-bit words. flag=1 -> int64 layout, flag=0 -> int32 layout.
// ---------------------------------------------------------------------------
__global__ __launch_bounds__(64)
void detect_kernel(const unsigned* __restrict__ ei_words, int* __restrict__ flag) {
    if (threadIdx.x == 0 && blockIdx.x == 0) {
        int allzero = 1;
        for (int i = 0; i < 64; ++i) {
            if (ei_words[2 * i + 1] != 0u) { allzero = 0; break; }
        }
        *flag = allzero;
    }
}

__device__ __forceinline__ void load_edge(const void* ei, int is64, int E, int i,
                                          int& s, int& t) {
    if (is64) {
        const long long* p = (const long long*)ei;
        s = (int)p[i];
        t = (int)p[E + i];
    } else {
        const int* p = (const int*)ei;
        s = p[i];
        t = p[E + i];
    }
}

// ---------------------------------------------------------------------------
// Tile sort: block t owns edges [t*TILE_E, (t+1)*TILE_E). Reads them into
// registers, LDS-histograms coarse bucket (dst>>NB_SHIFT), block-scans, and
// writes its PRIVATE tbuf tile in bucket order + tcnt/tstart[t][b].
// All global writes are block-exclusive -> no cross-block line ping-pong.
// ---------------------------------------------------------------------------
__global__ __launch_bounds__(256)
void tilesort_kernel(const void* __restrict__ ei, const int* __restrict__ flag,
                     unsigned* __restrict__ tbuf, int* __restrict__ tcnt,
                     int* __restrict__ tstart, int E, int B) {
    __shared__ int hist[BMAXPAD];
    __shared__ int wsum[8];
    const int t   = blockIdx.x;
    const int e0  = t * TILE_E;
    const int is64 = *flag;
    unsigned w[EPT];
    unsigned short bk[EPT];
    for (int i = threadIdx.x; i < BMAXPAD; i += 256) hist[i] = 0;
    __syncthreads();
#pragma unroll
    for (int k = 0; k < EPT; ++k) {
        const int i = e0 + k * 256 + (int)threadIdx.x;
        bk[k] = 0xFFFFu;
        w[k]  = 0u;
        if (i < E) {
            int s, d;
            load_edge(ei, is64, E, i, s, d);
            w[k]  = (unsigned)s | ((unsigned)(d & (NB - 1)) << 17);
            bk[k] = (unsigned short)(d >> NB_SHIFT);
            atomicAdd(&hist[bk[k]], 1);
        }
    }
    __syncthreads();
    // block exclusive scan over hist[0..BMAXPAD): 2 elems/thread
    const int lane = threadIdx.x & 63;
    const int wid  = threadIdx.x >> 6;
    const int v0 = hist[2 * threadIdx.x];
    const int v1 = hist[2 * threadIdx.x + 1];
    const int sum = v0 + v1;
    int incl = sum;
#pragma unroll
    for (int off = 1; off < 64; off <<= 1) {
        int tt = __shfl_up(incl, off, 64);
        if (lane >= off) incl += tt;
    }
    if (lane == 63) wsum[wid] = incl;
    __syncthreads();   // wsum ready; all hist reads (v0,v1) complete
    int woff = 0;
    for (int ww = 0; ww < wid; ++ww) woff += wsum[ww];
    const int excl = woff + incl - sum;
    hist[2 * threadIdx.x]     = excl;        // becomes write-pointer array
    hist[2 * threadIdx.x + 1] = excl + v0;
    const int b0 = 2 * threadIdx.x, b1 = 2 * threadIdx.x + 1;
    if (b0 < B) { tcnt[(size_t)t * B + b0] = v0; tstart[(size_t)t * B + b0] = excl; }
    if (b1 < B) { tcnt[(size_t)t * B + b1] = v1; tstart[(size_t)t * B + b1] = excl + v0; }
    __syncthreads();
#pragma unroll
    for (int k = 0; k < EPT; ++k) {
        if (bk[k] != 0xFFFFu) {
            const int pos = atomicAdd(&hist[bk[k]], 1);
            tbuf[(size_t)t * TILE_E + pos] = w[k];
        }
    }
}

// ---------------------------------------------------------------------------
// Transpose tcnt/tstart [T][B] -> [B][T] via 32x32 LDS tiles (both arrays).
// ---------------------------------------------------------------------------
__global__ __launch_bounds__(256)
void transpose2_kernel(const int* __restrict__ tcnt, const int* __restrict__ tstart,
                       int* __restrict__ tcntT, int* __restrict__ tstartT,
                       int T, int B) {
    __shared__ int ta[32][33];
    __shared__ int tb[32][33];
    const int bx = blockIdx.x;            // along B
    const int by = blockIdx.y;            // along T
    const int tx = threadIdx.x & 31;
    const int ty = threadIdx.x >> 5;      // 0..7
#pragma unroll
    for (int r = 0; r < 4; ++r) {
        const int trow = by * 32 + ty * 4 + r;   // t index
        const int bcol = bx * 32 + tx;           // b index
        if (trow < T && bcol < B) {
            ta[ty * 4 + r][tx] = tcnt[(size_t)trow * B + bcol];
            tb[ty * 4 + r][tx] = tstart[(size_t)trow * B + bcol];
        }
    }
    __syncthreads();
#pragma unroll
    for (int r = 0; r < 4; ++r) {
        const int brow = bx * 32 + ty * 4 + r;   // b index
        const int tcol = by * 32 + tx;           // t index
        if (brow < B && tcol < T) {
            tcntT[(size_t)brow * T + tcol]   = ta[tx][ty * 4 + r];
            tstartT[(size_t)brow * T + tcol] = tb[tx][ty * 4 + r];
        }
    }
}

// ---------------------------------------------------------------------------
// Three-kernel exclusive scan over tcntT (bucket-major) -> hbase.
// ---------------------------------------------------------------------------
__global__ __launch_bounds__(256)
void scan_partial_kernel(const int* __restrict__ cnt, int* __restrict__ bsum, int n) {
    const int base = blockIdx.x * 1024;
    int v = 0;
    for (int i = threadIdx.x; i < 1024; i += 256) {
        const int idx = base + i;
        v += (idx < n) ? cnt[idx] : 0;
    }
#pragma unroll
    for (int off = 32; off > 0; off >>= 1) v += __shfl_down(v, off, 64);
    __shared__ int ws[4];
    if ((threadIdx.x & 63) == 0) ws[threadIdx.x >> 6] = v;
    __syncthreads();
    if (threadIdx.x == 0) bsum[blockIdx.x] = ws[0] + ws[1] + ws[2] + ws[3];
}

__global__ __launch_bounds__(64)
void scan_bsum_kernel(int* __restrict__ bsum, int* __restrict__ total, int nb) {
    if (threadIdx.x == 0) {
        int run = 0;
        for (int i = 0; i < nb; ++i) { int t = bsum[i]; bsum[i] = run; run += t; }
        *total = run;
    }
}

__global__ __launch_bounds__(256)
void scan_final_kernel(const int* __restrict__ cnt, const int* __restrict__ bsum,
                       int* __restrict__ outp, int n) {
    const int base = blockIdx.x * 1024 + threadIdx.x * 4;
    int a0 = 0, a1 = 0, a2 = 0, a3 = 0;
    if (base + 0 < n) a0 = cnt[base + 0];
    if (base + 1 < n) a1 = cnt[base + 1];
    if (base + 2 < n) a2 = cnt[base + 2];
    if (base + 3 < n) a3 = cnt[base + 3];
    const int mysum = a0 + a1 + a2 + a3;
    const int lane = threadIdx.x & 63;
    const int wid  = threadIdx.x >> 6;
    int incl = mysum;
#pragma unroll
    for (int off = 1; off < 64; off <<= 1) {
        int t = __shfl_up(incl, off, 64);
        if (lane >= off) incl += t;
    }
    __shared__ int ws[4];
    if (lane == 63) ws[wid] = incl;
    __syncthreads();
    int woff = 0;
    for (int w = 0; w < wid; ++w) woff += ws[w];
    int pre = bsum[blockIdx.x] + woff + (incl - mysum);
    if (base + 0 < n) outp[base + 0] = pre; pre += a0;
    if (base + 1 < n) outp[base + 1] = pre; pre += a1;
    if (base + 2 < n) outp[base + 2] = pre; pre += a2;
    if (base + 3 < n) outp[base + 3] = pre;
}

// ---------------------------------------------------------------------------
// Fine sort: one block per bucket. Reads the bucket's runs from each tile
// (aux arrays coalesced via transposed layout), LDS-histograms the NB local
// dst ids, scans -> rowptr, then places esrc into the bucket's CONTIGUOUS
// region (block-exclusive writes).
// ---------------------------------------------------------------------------
__global__ __launch_bounds__(256)
void finesort_kernel(const unsigned* __restrict__ tbuf, const int* __restrict__ tcntT,
                     const int* __restrict__ tstartT, const int* __restrict__ hbase,
                     int* __restrict__ rowptr, int* __restrict__ esrc,
                     int n, int E, int T, int B) {
    __shared__ int hist[NB];
    __shared__ int wsum[4];
    const int b  = blockIdx.x;
    const int e0 = hbase[(size_t)b * T];
    hist[threadIdx.x] = 0;
    __syncthreads();
    for (int t = threadIdx.x; t < T; t += 256) {
        const int c  = tcntT[(size_t)b * T + t];
        const int ls = tstartT[(size_t)b * T + t];
        const unsigned* __restrict__ src = tbuf + (size_t)t * TILE_E + ls;
        for (int k = 0; k < c; ++k) atomicAdd(&hist[src[k] >> 17], 1);
    }
    __syncthreads();
    const int lane = threadIdx.x & 63;
    const int wid  = threadIdx.x >> 6;
    const int v = hist[threadIdx.x];
    int incl = v;
#pragma unroll
    for (int off = 1; off < 64; off <<= 1) {
        int tt = __shfl_up(incl, off, 64);
        if (lane >= off) incl += tt;
    }
    if (lane == 63) wsum[wid] = incl;
    __syncthreads();   // wsum ready; all hist reads complete
    int woff = 0;
    for (int w = 0; w < wid; ++w) woff += wsum[w];
    const int excl = woff + incl - v;
    hist[threadIdx.x] = e0 + excl;          // write pointers
    const int node = b * NB + (int)threadIdx.x;
    if (node < n) rowptr[node] = e0 + excl;
    if (b == 0 && threadIdx.x == 0) rowptr[n] = E;
    __syncthreads();
    for (int t = threadIdx.x; t < T; t += 256) {
        const int c  = tcntT[(size_t)b * T + t];
        const int ls = tstartT[(size_t)b * T + t];
        const unsigned* __restrict__ src = tbuf + (size_t)t * TILE_E + ls;
        for (int k = 0; k < c; ++k) {
            const unsigned wv = src[k];
            const int pos = atomicAdd(&hist[wv >> 17], 1);
            esrc[pos] = (int)(wv & 0x1FFFFu);
        }
    }
}

// ---------------------------------------------------------------------------
// Weight packing: WT[c][k] = Wcat[k][c] as bf16, row stride WT_LD.
// ---------------------------------------------------------------------------
__global__ __launch_bounds__(256)
void pack_dual_kernel(const float* __restrict__ Wl, const float* __restrict__ Wr,
                      ushort_t* __restrict__ WT) {
    int i = blockIdx.x * 256 + threadIdx.x;
    if (i >= 128 * 128) return;
    int k = i >> 7, c = i & 127;
    float v = (c < 64) ? Wl[k * 64 + c] : Wr[k * 64 + (c - 64)];
    WT[c * WT_LD + k] = f2bf(v);
}
__global__ __launch_bounds__(256)
void pack_stack_kernel(const float* __restrict__ Wl, const float* __restrict__ Wr,
                       ushort_t* __restrict__ WT) {
    int i = blockIdx.x * 256 + threadIdx.x;
    if (i >= 128 * 128) return;
    int k = i >> 7, c = i & 127;
    float v = (k < 64) ? Wl[k * 128 + c] : Wr[(k - 64) * 128 + c];
    WT[c * WT_LD + k] = f2bf(v);
}

// ---------------------------------------------------------------------------
// MFMA GEMM: C[n][128] (bf16) = A[n][128] @ W[128][128]  (+bias, tanh opt).
// ---------------------------------------------------------------------------
template <bool A_FP32, bool TANH_BIAS>
__global__ __launch_bounds__(256)
void mfma_gemm_kernel(const void* __restrict__ Av, const ushort_t* __restrict__ WT,
                      const float* __restrict__ bias, ushort_t* __restrict__ C, int n) {
    __shared__ ushort_t sW[128 * WT_LD];
    {
        const uint4* gsrc = (const uint4*)WT;
        uint4* ldst = (uint4*)sW;
        for (int i = threadIdx.x; i < 128 * WT_LD * 2 / 16; i += 256) ldst[i] = gsrc[i];
    }
    __syncthreads();
    const int lane = threadIdx.x & 63;
    const int wave = threadIdx.x >> 6;
    const int row0 = blockIdx.x * 64 + wave * 16;
    const int rA   = min(row0 + (lane & 15), n - 1);
    const int kg   = lane >> 4;       // 0..3

    bf16x8 a[4];
    if (A_FP32) {
        const float* A = (const float*)Av;
#pragma unroll
        for (int t = 0; t < 4; ++t) {
            const float4 lo = *(const float4*)(A + (size_t)rA * 128 + t * 32 + kg * 8);
            const float4 hi = *(const float4*)(A + (size_t)rA * 128 + t * 32 + kg * 8 + 4);
            const ushort4 u0 = f4_to_bf4(lo), u1 = f4_to_bf4(hi);
            bf16x8 av;
            av[0] = (short)u0.x; av[1] = (short)u0.y; av[2] = (short)u0.z; av[3] = (short)u0.w;
            av[4] = (short)u1.x; av[5] = (short)u1.y; av[6] = (short)u1.z; av[7] = (short)u1.w;
            a[t] = av;
        }
    } else {
        const ushort_t* A = (const ushort_t*)Av;
#pragma unroll
        for (int t = 0; t < 4; ++t)
            a[t] = *(const bf16x8*)(A + (size_t)rA * 128 + t * 32 + kg * 8);
    }

    f32x4 acc[8];
#pragma unroll
    for (int ct = 0; ct < 8; ++ct) acc[ct] = (f32x4)(0.f);

#pragma unroll
    for (int ct = 0; ct < 8; ++ct) {
        const int c0 = ct * 16 + (lane & 15);
#pragma unroll
        for (int t = 0; t < 4; ++t) {
            const bf16x8 b = *(const bf16x8*)(sW + (size_t)c0 * WT_LD + t * 32 + kg * 8);
            acc[ct] = __builtin_amdgcn_mfma_f32_16x16x32_bf16(a[t], b, acc[ct], 0, 0, 0);
        }
    }

    const int orow = row0 + kg * 4;
#pragma unroll
    for (int ct = 0; ct < 8; ++ct) {
        const int col = ct * 16 + (lane & 15);
        const float badd = TANH_BIAS ? bias[col] : 0.f;
#pragma unroll
        for (int i = 0; i < 4; ++i) {
            const int r = orow + i;
            if (r < n) {
                float v = acc[ct][i];
                if (TANH_BIAS) v = tanhf(v + badd);
                C[(size_t)r * 128 + col] = f2bf(v);
            }
        }
    }
}

// ---------------------------------------------------------------------------
// Gather-mean + residual + bias + tanh over concat buffer pq[n][128].
// OUTMODE 0: write ah[node][64+4c] (stride 128). OUTMODE 1: h[node][4c] (stride 64).
// ---------------------------------------------------------------------------
template <int OUTMODE>
__global__ __launch_bounds__(THREADS)
void gather_fuse_kernel(const int* __restrict__ rowptr, const int* __restrict__ esrc,
                        const ushort_t* __restrict__ pq, const float* __restrict__ bias,
                        ushort_t* __restrict__ hout, int n) {
    constexpr int CH  = 16;
    constexpr int NPB = THREADS / CH;
    const int node = blockIdx.x * NPB + (int)(threadIdx.x / CH);
    const int c    = threadIdx.x & (CH - 1);
    if (node >= n) return;
    const int begin = rowptr[node];
    const int end   = rowptr[node + 1];
    float4 acc = make_float4(0.f, 0.f, 0.f, 0.f);
    int e = begin;
    for (; e + 4 <= end; e += 4) {
        const int s0 = esrc[e + 0], s1 = esrc[e + 1], s2 = esrc[e + 2], s3 = esrc[e + 3];
        const float4 v0 = bf4_to_f4(*(const ushort4*)(pq + (size_t)s0 * 128 + 4 * c));
        const float4 v1 = bf4_to_f4(*(const ushort4*)(pq + (size_t)s1 * 128 + 4 * c));
        const float4 v2 = bf4_to_f4(*(const ushort4*)(pq + (size_t)s2 * 128 + 4 * c));
        const float4 v3 = bf4_to_f4(*(const ushort4*)(pq + (size_t)s3 * 128 + 4 * c));
        acc.x += v0.x + v1.x + v2.x + v3.x;
        acc.y += v0.y + v1.y + v2.y + v3.y;
        acc.z += v0.z + v1.z + v2.z + v3.z;
        acc.w += v0.w + v1.w + v2.w + v3.w;
    }
    for (; e < end; ++e) {
        const int s = esrc[e];
        const float4 v = bf4_to_f4(*(const ushort4*)(pq + (size_t)s * 128 + 4 * c));
        acc.x += v.x; acc.y += v.y; acc.z += v.z; acc.w += v.w;
    }
    const float inv = 1.0f / fmaxf((float)(end - begin), 1.0f);
    const float4 qv = bf4_to_f4(*(const ushort4*)(pq + (size_t)node * 128 + 64 + 4 * c));
    const float4 bv = *(const float4*)(bias + 4 * c);
    float4 o;
    o.x = tanhf(acc.x * inv + qv.x + bv.x);
    o.y = tanhf(acc.y * inv + qv.y + bv.y);
    o.z = tanhf(acc.z * inv + qv.z + bv.z);
    o.w = tanhf(acc.w * inv + qv.w + bv.w);
    if (OUTMODE == 0) {
        *(ushort4*)(hout + (size_t)node * 128 + 64 + 4 * c) = f4_to_bf4(o);
    } else {
        *(ushort4*)(hout + (size_t)node * 64 + 4 * c) = f4_to_bf4(o);
    }
}

// ---------------------------------------------------------------------------
// gather-mean into ah cols 0..63 reading ah cols 64..127 (disjoint ranges).
// ---------------------------------------------------------------------------
__global__ __launch_bounds__(THREADS)
void gather_mean_kernel(const int* __restrict__ rowptr, const int* __restrict__ esrc,
                        ushort_t* __restrict__ ah, int n) {
    constexpr int CH  = 16;
    constexpr int NPB = THREADS / CH;
    const int node = blockIdx.x * NPB + (int)(threadIdx.x / CH);
    const int c    = threadIdx.x & (CH - 1);
    if (node >= n) return;
    const int begin = rowptr[node];
    const int end   = rowptr[node + 1];
    float4 acc = make_float4(0.f, 0.f, 0.f, 0.f);
    int e = begin;
    for (; e + 4 <= end; e += 4) {
        const int s0 = esrc[e + 0], s1 = esrc[e + 1], s2 = esrc[e + 2], s3 = esrc[e + 3];
        const float4 v0 = bf4_to_f4(*(const ushort4*)(ah + (size_t)s0 * 128 + 64 + 4 * c));
        const float4 v1 = bf4_to_f4(*(const ushort4*)(ah + (size_t)s1 * 128 + 64 + 4 * c));
        const float4 v2 = bf4_to_f4(*(const ushort4*)(ah + (size_t)s2 * 128 + 64 + 4 * c));
        const float4 v3 = bf4_to_f4(*(const ushort4*)(ah + (size_t)s3 * 128 + 64 + 4 * c));
        acc.x += v0.x + v1.x + v2.x + v3.x;
        acc.y += v0.y + v1.y + v2.y + v3.y;
        acc.z += v0.z + v1.z + v2.z + v3.z;
        acc.w += v0.w + v1.w + v2.w + v3.w;
    }
    for (; e < end; ++e) {
        const int s = esrc[e];
        const float4 v = bf4_to_f4(*(const ushort4*)(ah + (size_t)s * 128 + 64 + 4 * c));
        acc.x += v.x; acc.y += v.y; acc.z += v.z; acc.w += v.w;
    }
    const float inv = 1.0f / fmaxf((float)(end - begin), 1.0f);
    ushort4 o = f4_to_bf4(make_float4(acc.x * inv, acc.y * inv, acc.z * inv, acc.w * inv));
    *(ushort4*)(ah + (size_t)node * 128 + 4 * c) = o;
}

// ---------------------------------------------------------------------------
// Head: out = h @ Wlin + blin   ([n,64] bf16 x [64,10] fp32) -> fp32.
// ---------------------------------------------------------------------------
__global__ __launch_bounds__(THREADS)
void head_kernel(const ushort_t* __restrict__ h, const float* __restrict__ W,
                 const float* __restrict__ bias, float* __restrict__ out, int n) {
    __shared__ float sW[64 * 10];
    __shared__ float sb[10];
    for (int i = threadIdx.x; i < 640; i += THREADS) sW[i] = W[i];
    if (threadIdx.x < 10) sb[threadIdx.x] = bias[threadIdx.x];
    __syncthreads();
    int idx = blockIdx.x * THREADS + threadIdx.x;
    if (idx >= n * 10) return;
    int row = idx / 10;
    int col = idx - row * 10;
    const ushort_t* __restrict__ hr = h + (size_t)row * 64;
    float acc = sb[col];
#pragma unroll 16
    for (int k = 0; k < 64; ++k) acc += bf2f(hr[k]) * sW[k * 10 + col];
    out[idx] = acc;
}

extern "C" void kernel_launch(void* const* d_in, const int* in_sizes, int n_in,
                              void* d_out, int out_size, void* d_ws, size_t ws_size,
                              hipStream_t stream) {
    const float* x    = (const float*)d_in[0];
    const void*  ei   = d_in[1];
    const float* W1l  = (const float*)d_in[2];
    const float* W1r  = (const float*)d_in[3];
    const float* b1   = (const float*)d_in[4];
    const float* W2l  = (const float*)d_in[5];
    const float* W2r  = (const float*)d_in[6];
    const float* b2   = (const float*)d_in[7];
    const float* W3l  = (const float*)d_in[8];
    const float* W3r  = (const float*)d_in[9];
    const float* b3   = (const float*)d_in[10];
    const float* Wlin = (const float*)d_in[11];
    const float* blin = (const float*)d_in[12];
    float* out = (float*)d_out;

    const int n = in_sizes[0] / 128;           // 100000
    const int E = in_sizes[1] / 2;             // 1600000
    const int B = (n + NB - 1) / NB;           // buckets (391)
    const int T = (E + TILE_E - 1) / TILE_E;   // sort tiles (391)
    const int Ctot = B * T;

    // --- workspace carve-up (~107 MB) ---
    char* ws = (char*)d_ws;
    size_t off = 0;
    auto carve = [&](size_t bytes) {
        void* p = ws + off;
        off += (bytes + 255) & ~(size_t)255;
        return p;
    };
    int*      flag    = (int*)     carve(256);
    int*      bsum    = (int*)     carve(4096);
    unsigned* tbuf    = (unsigned*)carve((size_t)T * TILE_E * 4);
    int*      tcnt    = (int*)     carve((size_t)Ctot * 4);
    int*      tstart  = (int*)     carve((size_t)Ctot * 4);
    int*      tcntT   = (int*)     carve((size_t)Ctot * 4);
    int*      tstartT = (int*)     carve((size_t)Ctot * 4);
    int*      hbase   = (int*)     carve((size_t)(Ctot + 1) * 4);
    int*      rowptr  = (int*)     carve((size_t)(n + 1) * 4);
    int*      esrc    = (int*)     carve((size_t)E * 4);
    ushort_t* WT1     = (ushort_t*)carve((size_t)128 * WT_LD * 2);
    ushort_t* WT2     = (ushort_t*)carve((size_t)128 * WT_LD * 2);
    ushort_t* WT3     = (ushort_t*)carve((size_t)128 * WT_LD * 2);
    ushort_t* pq      = (ushort_t*)carve((size_t)n * 128 * 2);  // GEMM1/3 out
    ushort_t* ah      = (ushort_t*)carve((size_t)n * 128 * 2);  // [agg|h1]
    ushort_t* h2      = (ushort_t*)carve((size_t)n * 128 * 2);
    ushort_t* h3      = (ushort_t*)carve((size_t)n * 64 * 2);
    (void)ws_size;

    const int cscan   = (Ctot + 1023) / 1024;
    const int gblocks = (n + 63) / 64;

    // --- weight packing (tiny) ---
    pack_dual_kernel <<<64, 256, 0, stream>>>(W1l, W1r, WT1);
    pack_stack_kernel<<<64, 256, 0, stream>>>(W2l, W2r, WT2);
    pack_dual_kernel <<<64, 256, 0, stream>>>(W3l, W3r, WT3);

    // --- tiled two-level edge sort (once; graph shared by all layers) ---
    detect_kernel<<<1, 64, 0, stream>>>((const unsigned*)ei, flag);
    tilesort_kernel<<<T, 256, 0, stream>>>(ei, flag, tbuf, tcnt, tstart, E, B);
    {
        dim3 tg((B + 31) / 32, (T + 31) / 32);
        transpose2_kernel<<<tg, 256, 0, stream>>>(tcnt, tstart, tcntT, tstartT, T, B);
    }
    scan_partial_kernel<<<cscan, 256, 0, stream>>>(tcntT, bsum, Ctot);
    scan_bsum_kernel<<<1, 64, 0, stream>>>(bsum, hbase + Ctot, cscan);
    scan_final_kernel<<<cscan, 256, 0, stream>>>(tcntT, bsum, hbase, Ctot);
    finesort_kernel<<<B, 256, 0, stream>>>(tbuf, tcntT, tstartT, hbase,
                                           rowptr, esrc, n, E, T, B);

    // --- layer 1: pq = x @ [W1l|W1r]; h1 = tanh(mean(p) + q + b1) -> ah[:,64:] ---
    mfma_gemm_kernel<true, false><<<gblocks, 256, 0, stream>>>(x, WT1, nullptr, pq, n);
    gather_fuse_kernel<0><<<(n + 15) / 16, THREADS, 0, stream>>>(
        rowptr, esrc, pq, b1, ah, n);

    // --- layer 2: ah[:,0:64] = mean(h1); h2 = tanh(ah @ [W2l;W2r] + b2) ---
    gather_mean_kernel<<<(n + 15) / 16, THREADS, 0, stream>>>(rowptr, esrc, ah, n);
    mfma_gemm_kernel<false, true><<<gblocks, 256, 0, stream>>>(ah, WT2, b2, h2, n);

    // --- layer 3: pq = h2 @ [W3l|W3r]; h3 = tanh(mean(p) + q + b3) ---
    mfma_gemm_kernel<false, false><<<gblocks, 256, 0, stream>>>(h2, WT3, nullptr, pq, n);
    gather_fuse_kernel<1><<<(n + 15) / 16, THREADS, 0, stream>>>(
        rowptr, esrc, pq, b3, h3, n);

    // --- head ---
    head_kernel<<<(n * 10 + THREADS - 1) / THREADS, THREADS, 0, stream>>>(
        h3, Wlin, blin, out, n);
}